// Round 11
// baseline (182.834 us; speedup 1.0000x reference)
//
#include <hip/hip_runtime.h>
#include <hip/hip_bf16.h>
#include <math.h>

typedef __attribute__((ext_vector_type(8))) short short8;
typedef __attribute__((ext_vector_type(4))) short short4v;
typedef __attribute__((ext_vector_type(4))) float f32x4;

#define DEV __device__ __forceinline__

DEV short f2bf(float f) {
  unsigned u = __builtin_bit_cast(unsigned, f);
  unsigned r = (u + 0x7FFFu + ((u >> 16) & 1u)) >> 16;
  return (short)r;
}

DEV float bf2f(short s) {
  unsigned u = ((unsigned)(unsigned short)s) << 16;
  return __builtin_bit_cast(float, u);
}

DEV short f2h(float f) {
  _Float16 h = (_Float16)f;
  return __builtin_bit_cast(short, h);
}

DEV float h2f(short s) {
  return (float)__builtin_bit_cast(_Float16, s);
}

DEV unsigned cvt_pk_bf16(float lo, float hi) {
  unsigned r;
  asm("v_cvt_pk_bf16_f32 %0, %1, %2" : "=v"(r) : "v"(lo), "v"(hi));
  return r;
}

DEV void gload_lds16(const void* g, void* l) {
  __builtin_amdgcn_global_load_lds((const __attribute__((address_space(1))) void*)g,
                                   (__attribute__((address_space(3))) void*)l, 16, 0, 0);
}

// gemm1 FUSED with qkv_post: C = xb[2048 x 2048] * WTqkv[3072 x 2048]^T, then the
// epilogue applies rope+rmsnorm (q,k) / gate+ve (v) directly from an LDS tile.
// BM=64, BN=128 (= exactly one head), BK=64, XOR-swizzle, 2-phase dbuf, XCD swizzle.
__global__ __launch_bounds__(256) void gemm_qkv_fused(const short* __restrict__ A,
                                                      const short* __restrict__ BT,
                                                      const float* __restrict__ cosb,
                                                      const float* __restrict__ sinb,
                                                      const float* __restrict__ x,
                                                      const float* __restrict__ ve,
                                                      const float* __restrict__ Wg,
                                                      float* __restrict__ outPK,
                                                      float* __restrict__ outPV,
                                                      short* __restrict__ qb,
                                                      short* __restrict__ kb) {
  const int K = 2048;
  __shared__ __attribute__((aligned(16))) char smem[49152];
  short* As0 = (short*)smem;             // 2 bufs x 64x64 shorts  (16 KB)
  short* Bs0 = (short*)(smem + 16384);   // 2 bufs x 128x64 shorts (32 KB)
  const int tid = threadIdx.x;
  const int w = tid >> 6, l = tid & 63;
  const int g = l >> 4, lr = l & 15;
  int nbx = gridDim.x, nwg = nbx * gridDim.y;
  int flat = blockIdx.y * nbx + blockIdx.x;
  int qq = nwg >> 3;
  int f2 = (flat & 7) * qq + (flat >> 3);
  const int m0 = (f2 / nbx) * 64;
  const int j = f2 % nbx;                // head selector: <16 q, 16-19 k, 20-23 v
  const int n0 = j * 128;
  const int wr = w >> 1, wc = w & 1;
  f32x4 acc[2][4] = {};

  auto stage = [&](int buf, int k0) {
#pragma unroll
    for (int it = 0; it < 2; ++it) {
      int idx = it * 256 + tid;
      int row = idx >> 3;
      int scol = ((idx & 7) * 16) ^ ((row & 7) << 4);
      gload_lds16(A + (size_t)(m0 + row) * K + k0 + (scol >> 1), As0 + buf * 4096 + idx * 8);
    }
#pragma unroll
    for (int it = 0; it < 4; ++it) {
      int idx = it * 256 + tid;
      int row = idx >> 3;
      int scol = ((idx & 7) * 16) ^ ((row & 7) << 4);
      gload_lds16(BT + (size_t)(n0 + row) * K + k0 + (scol >> 1), Bs0 + buf * 8192 + idx * 8);
    }
  };

  stage(0, 0);
  __syncthreads();
  int cur = 0;
  for (int k0 = 0; k0 < K; k0 += 64) {
    if (k0 + 64 < K) stage(cur ^ 1, k0 + 64);
#pragma unroll
    for (int ki = 0; ki < 2; ++ki) {
      const int kcol = (ki * 64 + g * 16) ^ ((lr & 7) << 4);
      short8 af[2], bfr[4];
#pragma unroll
      for (int i = 0; i < 2; ++i)
        af[i] = *(const short8*)(As0 + cur * 4096 + (((wr * 32 + i * 16 + lr) * 128 + kcol) >> 1));
#pragma unroll
      for (int i = 0; i < 4; ++i)
        bfr[i] = *(const short8*)(Bs0 + cur * 8192 + (((wc * 64 + i * 16 + lr) * 128 + kcol) >> 1));
#pragma unroll
      for (int mi = 0; mi < 2; ++mi)
#pragma unroll
        for (int ni = 0; ni < 4; ++ni)
          acc[mi][ni] = __builtin_amdgcn_mfma_f32_16x16x32_bf16(af[mi], bfr[ni], acc[mi][ni], 0, 0, 0);
    }
    __syncthreads();
    cur ^= 1;
  }
  // ---- fused epilogue: acc -> LDS f32 tile [64][132] (pad kills row-bank alias) ----
  float* tile = (float*)smem;  // 64*132*4 = 33792 B, fits; staging LDS is dead now
#pragma unroll
  for (int mi = 0; mi < 2; ++mi)
#pragma unroll
    for (int ni = 0; ni < 4; ++ni) {
      int rrow = wr * 32 + mi * 16 + g * 4;
      int col = wc * 64 + ni * 16 + lr;
#pragma unroll
      for (int r = 0; r < 4; ++r)
        tile[(rrow + r) * 132 + col] = acc[mi][ni][r];
    }
  __syncthreads();
  // each wave: 16 rows, lane l = column pair (l, l+64)
  const float SCQ = 0.08838834764831845f * 1.4426950408889634f;
  for (int rr = 0; rr < 16; ++rr) {
    int tl = w * 16 + rr;
    int t = m0 + tl;
    float x1 = tile[tl * 132 + l];
    float x2 = tile[tl * 132 + 64 + l];
    if (j < 20) {
      float c = cosb[t * 64 + l], s = sinb[t * 64 + l];
      float lo = x1 * c + x2 * s;
      float hi = x2 * c - x1 * s;
      float ss = lo * lo + hi * hi;
#pragma unroll
      for (int d = 1; d < 64; d <<= 1) ss += __shfl_xor(ss, d, 64);
      float r = rsqrtf(ss * (1.0f / 128.0f) + 1e-6f) * 1.2f;
      if (j < 16) {
        float rq = r * SCQ;
        size_t b = ((size_t)j * 2048 + t) * 128;
        qb[b + l] = f2bf(lo * rq);
        qb[b + 64 + l] = f2bf(hi * rq);
      } else {
        lo *= r; hi *= r;
        int kvh = j - 16;
        size_t b = ((size_t)(2048 + t) * 4 + kvh) * 128;
        outPK[b + l] = lo;
        outPK[b + 64 + l] = hi;
        size_t b2 = ((size_t)kvh * 4096 + 2048 + t) * 128;
        kb[b2 + l] = f2bf(lo);
        kb[b2 + 64 + l] = f2bf(hi);
      }
    } else {
      int kv = j - 20;
      float z = 0.f;
#pragma unroll
      for (int jj = 0; jj < 12; ++jj) z += x[(size_t)t * 2048 + jj] * Wg[jj * 4 + kv];
      float gate = 3.0f / (1.0f + expf(-z));
      const float* vei = ve + (size_t)t * 512 + kv * 128;
      float v0 = x1 + gate * vei[l];
      float v1 = x2 + gate * vei[64 + l];
      size_t b = ((size_t)(2048 + t) * 4 + kv) * 128;
      outPV[b + l] = v0;
      outPV[b + 64 + l] = v1;
    }
  }
}

// gemm2: m64 GEMM, f32 out (R9-proven). BM=64, BN=128, BK=64.
__global__ __launch_bounds__(256) void gemm_m64_f32(const short* __restrict__ A,
                                                    const short* __restrict__ BT,
                                                    float* __restrict__ C,
                                                    int M, int N, int K) {
  __shared__ __attribute__((aligned(16))) short As[2][64 * 64];
  __shared__ __attribute__((aligned(16))) short Bs[2][128 * 64];
  const int tid = threadIdx.x;
  const int w = tid >> 6, l = tid & 63;
  const int g = l >> 4, lr = l & 15;
  int nbx = gridDim.x, nwg = nbx * gridDim.y;
  int flat = blockIdx.y * nbx + blockIdx.x;
  int qq = nwg >> 3;
  int f2 = (flat & 7) * qq + (flat >> 3);
  const int m0 = (f2 / nbx) * 64, n0 = (f2 % nbx) * 128;
  const int wr = w >> 1, wc = w & 1;
  f32x4 acc[2][4] = {};

  auto stage = [&](int buf, int k0) {
#pragma unroll
    for (int it = 0; it < 2; ++it) {
      int idx = it * 256 + tid;
      int row = idx >> 3;
      int scol = ((idx & 7) * 16) ^ ((row & 7) << 4);
      gload_lds16(A + (size_t)(m0 + row) * K + k0 + (scol >> 1), As[buf] + idx * 8);
    }
#pragma unroll
    for (int it = 0; it < 4; ++it) {
      int idx = it * 256 + tid;
      int row = idx >> 3;
      int scol = ((idx & 7) * 16) ^ ((row & 7) << 4);
      gload_lds16(BT + (size_t)(n0 + row) * K + k0 + (scol >> 1), Bs[buf] + idx * 8);
    }
  };

  stage(0, 0);
  __syncthreads();
  int cur = 0;
  for (int k0 = 0; k0 < K; k0 += 64) {
    if (k0 + 64 < K) stage(cur ^ 1, k0 + 64);
#pragma unroll
    for (int ki = 0; ki < 2; ++ki) {
      const int kcol = (ki * 64 + g * 16) ^ ((lr & 7) << 4);
      short8 af[2], bfr[4];
#pragma unroll
      for (int i = 0; i < 2; ++i)
        af[i] = *(const short8*)(As[cur] + (((wr * 32 + i * 16 + lr) * 128 + kcol) >> 1));
#pragma unroll
      for (int i = 0; i < 4; ++i)
        bfr[i] = *(const short8*)(Bs[cur] + (((wc * 64 + i * 16 + lr) * 128 + kcol) >> 1));
#pragma unroll
      for (int mi = 0; mi < 2; ++mi)
#pragma unroll
        for (int ni = 0; ni < 4; ++ni)
          acc[mi][ni] = __builtin_amdgcn_mfma_f32_16x16x32_bf16(af[mi], bfr[ni], acc[mi][ni], 0, 0, 0);
    }
    __syncthreads();
    cur ^= 1;
  }
#pragma unroll
  for (int mi = 0; mi < 2; ++mi)
#pragma unroll
    for (int ni = 0; ni < 4; ++ni) {
      int row = m0 + wr * 32 + mi * 16 + g * 4;
      int col = n0 + wc * 64 + ni * 16 + lr;
#pragma unroll
      for (int r = 0; r < 4; ++r)
        C[(size_t)(row + r) * N + col] = acc[mi][ni][r];
    }
}

// Fused prep: bid<4096 -> cvt_x; else the 4 weight transposes (flattened 160x64).
__global__ __launch_bounds__(256) void prep(const float* __restrict__ x,
                                            short* __restrict__ xb,
                                            const float* __restrict__ Wq,
                                            const float* __restrict__ Wk,
                                            const float* __restrict__ Wv,
                                            const float* __restrict__ Wo,
                                            short* __restrict__ WTqkv,
                                            short* __restrict__ WToT) {
  __shared__ float tile[32][33];
  int bid = blockIdx.x;
  int tid = threadIdx.x;
  if (bid < 4096) {
    int i = bid * 256 + tid;
    float4 v = ((const float4*)x)[i];
    short4v o;
    o.x = f2bf(v.x); o.y = f2bf(v.y); o.z = f2bf(v.z); o.w = f2bf(v.w);
    ((short4v*)xb)[i] = o;
    return;
  }
  int b = bid - 4096;
  int bx = b % 160, by = b / 160;
  const float* W;
  short* WT;
  int N, cb;
  if (bx < 64) { W = Wq; WT = WTqkv; N = 2048; cb = bx; }
  else if (bx < 80) { W = Wk; WT = WTqkv + (size_t)2048 * 2048; N = 512; cb = bx - 64; }
  else if (bx < 96) { W = Wv; WT = WTqkv + (size_t)2560 * 2048; N = 512; cb = bx - 80; }
  else { W = Wo; WT = WToT; N = 2048; cb = bx - 96; }
  int tx = tid & 31, ty = tid >> 5;
  int c0 = cb * 32, r0 = by * 32;
#pragma unroll
  for (int i = 0; i < 4; ++i)
    tile[ty + i * 8][tx] = W[(size_t)(r0 + ty + i * 8) * N + c0 + tx];
  __syncthreads();
#pragma unroll
  for (int i = 0; i < 4; ++i)
    WT[(size_t)(c0 + ty + i * 8) * 2048 + r0 + tx] = f2bf(tile[tx][ty + i * 8]);
}

// past copy, K only (PV handled by v_transpose).
__global__ __launch_bounds__(256) void past_copy(const float* __restrict__ pk,
                                                 float* __restrict__ outPK,
                                                 short* __restrict__ kb) {
  int i = blockIdx.x * 256 + threadIdx.x;  // 0..1048575
  int d = i & 127, kv = (i >> 7) & 3, s = i >> 9;
  float a = pk[i];
  outPK[i] = a;
  kb[((size_t)kv * 4096 + s) * 128 + d] = f2bf(a);
}

// vbT transpose + past-PV copy fused: rows < 2048 read pv (and write outPV);
// rows >= 2048 read outPV (written by gemm_qkv_fused). grid (16, 128), block 256.
__global__ __launch_bounds__(256) void v_transpose(const float* __restrict__ pv,
                                                   float* __restrict__ outPV,
                                                   short* __restrict__ vbT) {
  __shared__ float tile[32][33];
  int tx = threadIdx.x & 31, ty = threadIdx.x >> 5;
  int c0 = blockIdx.x * 32, r0 = blockIdx.y * 32;
  if (r0 < 2048) {
#pragma unroll
    for (int i = 0; i < 4; ++i) {
      float v = pv[(size_t)(r0 + ty + i * 8) * 512 + c0 + tx];
      tile[ty + i * 8][tx] = v;
      outPV[(size_t)(r0 + ty + i * 8) * 512 + c0 + tx] = v;
    }
  } else {
#pragma unroll
    for (int i = 0; i < 4; ++i)
      tile[ty + i * 8][tx] = outPV[(size_t)(r0 + ty + i * 8) * 512 + c0 + tx];
  }
  __syncthreads();
#pragma unroll
  for (int i = 0; i < 4; ++i)
    vbT[(size_t)(c0 + ty + i * 8) * 4096 + r0 + tx] = f2bf(tile[tx][ty + i * 8]);
}

// flash attention, 2-way key-split (frozen R8 structure, ~86 us).
__global__ __launch_bounds__(256, 2) void attn(const short* __restrict__ qb,
                                               const short* __restrict__ kb,
                                               const short* __restrict__ vbT,
                                               short* __restrict__ Po,
                                               float* __restrict__ ml) {
  extern __shared__ __attribute__((aligned(16))) short smem[];
  short* Ks = smem;           // [2][64][128] shorts, swizzled
  short* Vs = smem + 16384;   // [2][128][64] shorts, swizzled
  const int tid = threadIdx.x, w = tid >> 6, l = tid & 63;
  const int g = l >> 4, lr = l & 15;
  const int lid = blockIdx.x;
  const int qbi = 15 - (lid >> 5);
  const int sub = lid & 31;
  const int h = sub >> 1, cls = sub & 1;
  const int kv = h >> 2;
  const int qw = qbi * 128 + w * 32;
  char* Pw = (char*)(smem + 32768) + w * 2048;
  const short* gK = kb + (size_t)kv * 4096 * 128;
  const short* gV = vbT + (size_t)kv * 128 * 4096;
  const int nT = 34 + 2 * qbi;
  const int cnt = (nT - cls + 1) >> 1;

  short8 aq[2][4];
#pragma unroll
  for (int u = 0; u < 2; ++u)
#pragma unroll
    for (int c4 = 0; c4 < 4; ++c4)
      aq[u][c4] = *(const short8*)(qb + ((size_t)(h * 2048 + qw + u * 16 + lr)) * 128 + c4 * 32 + g * 8);

  float m_r[2] = {-INFINITY, -INFINITY};
  float l_r[2] = {0.f, 0.f};
  f32x4 o[2][8] = {};

  const int rK = tid >> 4, cKs = ((tid & 15) * 16) ^ ((rK & 7) << 4);
  const int rV = tid >> 3, cVs = ((tid & 7) * 16) ^ ((rV & 7) << 4);
  const short* kptr = gK + (size_t)(cls * 64 + rK) * 128 + (cKs >> 1);
  const short* vptr = gV + (size_t)rV * 4096 + cls * 64 + (cVs >> 1);
  short* kdst = Ks + w * 512;
  short* vdst = Vs + w * 512;

  auto stageK = [&](int buf) {
#pragma unroll
    for (int it = 0; it < 4; ++it)
      gload_lds16(kptr + it * 2048, kdst + buf * 8192 + it * 2048);
    kptr += 16384;
  };
  auto stageV = [&](int buf) {
#pragma unroll
    for (int it = 0; it < 4; ++it)
      gload_lds16(vptr + (size_t)it * 131072, vdst + buf * 8192 + it * 2048);
    vptr += 128;
  };

  stageK(0);
  stageV(0);
  __syncthreads();
  int cur = 0;
  for (int i = 0; i < cnt; ++i) {
    const int s0 = (cls + 2 * i) * 64;
    if (i + 1 < cnt) {
      stageK(cur ^ 1);
      stageV(cur ^ 1);
    }
    f32x4 sc[2][4] = {};
    __builtin_amdgcn_s_setprio(1);
#pragma unroll
    for (int cc = 0; cc < 4; ++cc) {
      const int rb = cur * 8192 + (cc * 16 + lr) * 128;
      short8 bk[4];
#pragma unroll
      for (int c4 = 0; c4 < 4; ++c4)
        bk[c4] = *(const short8*)(Ks + rb + (((c4 * 64 + g * 16) ^ ((lr & 7) << 4)) >> 1));
#pragma unroll
      for (int c4 = 0; c4 < 4; ++c4) {
        sc[0][cc] = __builtin_amdgcn_mfma_f32_16x16x32_bf16(bk[c4], aq[0][c4], sc[0][cc], 0, 0, 0);
        sc[1][cc] = __builtin_amdgcn_mfma_f32_16x16x32_bf16(bk[c4], aq[1][c4], sc[1][cc], 0, 0, 0);
      }
    }
    __builtin_amdgcn_s_setprio(0);
    if (s0 + 63 > 2048 + qw) {
#pragma unroll
      for (int u = 0; u < 2; ++u)
#pragma unroll
        for (int cc = 0; cc < 4; ++cc)
#pragma unroll
          for (int r = 0; r < 4; ++r)
            sc[u][cc][r] = (s0 + cc * 16 + g * 4 + r <= 2048 + qw + u * 16 + lr)
                               ? sc[u][cc][r] : -INFINITY;
    }
    short8 ap[2][2];
#pragma unroll
    for (int u = 0; u < 2; ++u) {
      float pmax = -INFINITY;
#pragma unroll
      for (int cc = 0; cc < 4; ++cc) {
        float a = fmaxf(fmaxf(sc[u][cc][0], sc[u][cc][1]), fmaxf(sc[u][cc][2], sc[u][cc][3]));
        pmax = fmaxf(pmax, a);
      }
      if (!__all(pmax - m_r[u] <= 8.0f)) {
        float tm = fmaxf(pmax, __shfl_xor(pmax, 16, 64));
        tm = fmaxf(tm, __shfl_xor(tm, 32, 64));
        float mn = fmaxf(m_r[u], tm);
        float corr = exp2f(m_r[u] - mn);
        m_r[u] = mn;
        l_r[u] *= corr;
        float co[4];
#pragma unroll
        for (int r = 0; r < 4; ++r) co[r] = __shfl(corr, (l & 48) | (g * 4 + r), 64);
#pragma unroll
        for (int d8 = 0; d8 < 8; ++d8) {
          f32x4 tt = o[u][d8];
#pragma unroll
          for (int r = 0; r < 4; ++r) tt[r] *= co[r];
          o[u][d8] = tt;
        }
      }
      float ps = 0.f;
#pragma unroll
      for (int cc = 0; cc < 4; ++cc) {
        float p0 = exp2f(sc[u][cc][0] - m_r[u]);
        float p1 = exp2f(sc[u][cc][1] - m_r[u]);
        float p2 = exp2f(sc[u][cc][2] - m_r[u]);
        float p3 = exp2f(sc[u][cc][3] - m_r[u]);
        ps += (p0 + p1) + (p2 + p3);
        unsigned pk0 = cvt_pk_bf16(p0, p1);
        unsigned pk1 = cvt_pk_bf16(p2, p3);
        int off8 = (lr * 128 + cc * 32 + g * 8) ^ ((lr & 7) << 4);
        unsigned long long pq = (unsigned long long)pk0 | ((unsigned long long)pk1 << 32);
        *(unsigned long long*)(Pw + off8) = pq;
      }
      l_r[u] += ps;
#pragma unroll
      for (int ks = 0; ks < 2; ++ks)
        ap[u][ks] = *(const short8*)(Pw + ((lr * 128 + ks * 64 + g * 16) ^ ((lr & 7) << 4)));
    }
    __builtin_amdgcn_s_setprio(1);
#pragma unroll
    for (int d8 = 0; d8 < 8; ++d8) {
      const int rb = cur * 8192 + (d8 * 16 + lr) * 64;
      short8 bv0 = *(const short8*)(Vs + rb + (((0 * 64 + g * 16) ^ ((lr & 7) << 4)) >> 1));
      short8 bv1 = *(const short8*)(Vs + rb + (((1 * 64 + g * 16) ^ ((lr & 7) << 4)) >> 1));
      o[0][d8] = __builtin_amdgcn_mfma_f32_16x16x32_bf16(ap[0][0], bv0, o[0][d8], 0, 0, 0);
      o[0][d8] = __builtin_amdgcn_mfma_f32_16x16x32_bf16(ap[0][1], bv1, o[0][d8], 0, 0, 0);
      o[1][d8] = __builtin_amdgcn_mfma_f32_16x16x32_bf16(ap[1][0], bv0, o[1][d8], 0, 0, 0);
      o[1][d8] = __builtin_amdgcn_mfma_f32_16x16x32_bf16(ap[1][1], bv1, o[1][d8], 0, 0, 0);
    }
    __builtin_amdgcn_s_setprio(0);
    __syncthreads();
    cur ^= 1;
  }
#pragma unroll
  for (int u = 0; u < 2; ++u) {
    float ls = l_r[u];
    ls += __shfl_xor(ls, 16, 64);
    ls += __shfl_xor(ls, 32, 64);
    float inv = 1.0f / ls;
    float invo[4];
#pragma unroll
    for (int r = 0; r < 4; ++r) invo[r] = __shfl(inv, (l & 48) | (g * 4 + r), 64);
#pragma unroll
    for (int d8 = 0; d8 < 8; ++d8)
#pragma unroll
      for (int r = 0; r < 4; ++r)
        Po[((size_t)(cls * 16 + h) * 2048 + qw + u * 16 + g * 4 + r) * 128 + d8 * 16 + lr] =
            f2h(o[u][d8][r] * invo[r]);
    if (g == 0) {
      float2 v;
      v.x = m_r[u];
      v.y = ls;
      ((float2*)ml)[(size_t)(cls * 16 + h) * 2048 + qw + u * 16 + lr] = v;
    }
  }
}

// merge 2 key-split partials -> ya (bf16). one thread per (q, h, 8-d chunk).
__global__ __launch_bounds__(256) void attn_merge(const short* __restrict__ Po,
                                                  const float* __restrict__ ml,
                                                  short* __restrict__ ya) {
  int i = blockIdx.x * 256 + threadIdx.x;  // 0..524287
  int q = i >> 8, rem = i & 255, h = rem >> 4, oct = rem & 15;
  float mc[2], lc[2];
#pragma unroll
  for (int c = 0; c < 2; ++c) {
    float2 v = ((const float2*)ml)[(size_t)(c * 16 + h) * 2048 + q];
    mc[c] = v.x; lc[c] = v.y;
  }
  float m = fmaxf(mc[0], mc[1]);
  float wsum = 0.f, acc[8] = {};
#pragma unroll
  for (int c = 0; c < 2; ++c) {
    float wc = lc[c] * exp2f(mc[c] - m);
    wsum += wc;
    short8 p = *(const short8*)(Po + ((size_t)(c * 16 + h) * 2048 + q) * 128 + oct * 8);
#pragma unroll
    for (int j = 0; j < 8; ++j) acc[j] += wc * h2f(p[j]);
  }
  float inv = 1.0f / wsum;
  short8 ov;
#pragma unroll
  for (int j = 0; j < 8; ++j) ov[j] = f2bf(acc[j] * inv);
  *(short8*)(ya + (size_t)q * 2048 + h * 128 + oct * 8) = ov;
}

extern "C" void kernel_launch(void* const* d_in, const int* in_sizes, int n_in,
                              void* d_out, int out_size, void* d_ws, size_t ws_size,
                              hipStream_t stream) {
  const float* x = (const float*)d_in[0];
  const float* ve = (const float*)d_in[1];
  const float* cosb = (const float*)d_in[2];
  const float* sinb = (const float*)d_in[3];
  const float* past_key = (const float*)d_in[4];
  const float* past_value = (const float*)d_in[5];
  const float* Wq = (const float*)d_in[6];
  const float* Wk = (const float*)d_in[7];
  const float* Wv = (const float*)d_in[8];
  const float* Wo = (const float*)d_in[9];
  const float* Wg = (const float*)d_in[10];

  float* outY = (float*)d_out;          // 2048*2048
  float* outPK = outY + 4194304;        // 4096*4*128
  float* outPV = outPK + 2097152;       // 4096*4*128

  short* base = (short*)d_ws;
  short* WToT = base;                               // 2048*2048 bf16 (live to the end)
  short* WTqkv = base + 4194304;                    // 3072*2048 bf16  (dead after gemm1)
  short* xb = WTqkv + (size_t)6291456;              // 2048*2048 bf16  (dead after gemm1)
  short* qb = xb + (size_t)4194304 + 12582912;      // 16*2048*128 bf16 (address kept stable)
  short* kb = qb + (size_t)4194304;                 // 4*4096*128 bf16
  short* vbT = kb + (size_t)2097152;                // 4*128*4096 bf16 (transposed)
  short* ya = vbT + (size_t)2097152;                // 2048*2048 bf16
  // attn partials alias the dead WTqkv/xb pool:
  short* Po = WTqkv;                                // 2*16*2048*128 f16 = 8388608 shorts
  float* mlb = (float*)(base + 20971520);           // 2*16*2048 float2 = 524288 floats

  static bool attr_set = false;
  if (!attr_set) {
    (void)hipFuncSetAttribute((const void*)attn,
                              hipFuncAttributeMaxDynamicSharedMemorySize, 73728);
    attr_set = true;
  }

  prep<<<14336, 256, 0, stream>>>(x, xb, Wq, Wk, Wv, Wo, WTqkv, WToT);

  gemm_qkv_fused<<<dim3(24, 32), 256, 0, stream>>>(xb, WTqkv, cosb, sinb, x, ve, Wg,
                                                   outPK, outPV, qb, kb);

  past_copy<<<4096, 256, 0, stream>>>(past_key, outPK, kb);
  v_transpose<<<dim3(16, 128), 256, 0, stream>>>(past_value, outPV, vbT);

  attn<<<512, 256, 73728, stream>>>(qb, kb, vbT, Po, mlb);
  attn_merge<<<2048, 256, 0, stream>>>(Po, mlb, ya);

  gemm_m64_f32<<<dim3(16, 32), 256, 0, stream>>>(ya, WToT, outY, 2048, 2048, 2048);
}